// Round 7
// baseline (60.169 us; speedup 1.0000x reference)
//
#include <hip/hip_runtime.h>
#include <math.h>

#define DIM 512
#define CD 14
#define NCODES 16384
#define NTOK 8192
#define EPS 1e-5f
#define LOG_EPS -11.5129254650f  // log(1e-5)
#define PTHRESH 1e-12f           // below this, p is invisible to f32 accumulation

// ws float layout:
//   [0 .. 16383]      avg_prob accumulators (atomic; zeroed by hipMemsetAsync)
//   [16384 .. 18431]  per-block entropy partials (plain writes, every call)
//   [18432 .. 20479]  per-block commit partials  (plain writes, every call)
#define WS_ENT 16384
#define WS_COM (16384 + 2048)
#define NBLK (NTOK / 4)   // 2048 blocks, 4 tokens each

// Fused: numpy-emulated h (phase 1) + project_out + sparse clipped-softmax (phase 2).
//
// Phase 1 is a bit-exact emulation of numpy f32 einsum('bnd,cd->bnc'):
// sum_of_products_contig_contig_outstride0_two, BASELINE SIMD (SSE2/SSE3):
// 4 npyv lanes (no FMA: separate mul+add — hence fp contract(off)), 16-elem
// blocks, sub-block chain order 3,2,1,0, reduce (l0+l1)+(l2+l3) via hadd,
// then one f32 add of b_in[c]. VALIDATED rounds 3-6. DO NOT change arithmetic.
// (contract(off) is function-wide; phase 2 uses explicit fmaf, which still fuses.)
__global__ __launch_bounds__(256) void k_main(
    const float* __restrict__ x, const float* __restrict__ W_in,
    const float* __restrict__ b_in, const float* __restrict__ W_out,
    const float* __restrict__ b_out, float* __restrict__ out,
    float* __restrict__ idx_out, float* __restrict__ ws)
{
#pragma clang fp contract(off)
    __shared__ float h_lds[4][16];
    __shared__ float f_lds[4][16];
    __shared__ float entred[4], comred[4];

    const int tid  = threadIdx.x;
    const int wave = tid >> 6, lane = tid & 63;

    // ---- phase 1: 56 dots (4 tokens x 14 channels), 4 SSE-lane threads each ----
    const int dot = tid >> 2;   // 0..63, need 0..55
    const int j   = tid & 3;    // SSE lane
    if (dot < 4 * CD) {
        const int tt = dot / CD;
        const int c  = dot - tt * CD;
        const int t  = blockIdx.x * 4 + tt;
        const float* xp = x + (size_t)t * DIM + j;
        const float* wp = W_in + (size_t)c * DIM + j;

        float a = 0.f;
        #pragma unroll 4
        for (int i = 0; i < 32; ++i) {
            const int base = i * 16;
            const float x3 = xp[base + 12], w3 = wp[base + 12];
            const float x2 = xp[base + 8],  w2 = wp[base + 8];
            const float x1 = xp[base + 4],  w1 = wp[base + 4];
            const float x0 = xp[base + 0],  w0 = wp[base + 0];
            a = (x3 * w3) + a;   // s=3 sub-block first (npy chain order)
            a = (x2 * w2) + a;
            a = (x1 * w1) + a;
            a = (x0 * w0) + a;
        }
        // hadd pairing: (a0+a1) + (a2+a3), lanes grouped 4-aligned
        const float s2  = a + __shfl_xor(a, 1);
        const float sum = s2 + __shfl_xor(s2, 2);
        if (j == 0) {
            const float hv = sum + b_in[c];
            h_lds[tt][c] = hv;
            f_lds[tt][c] = __expf(-400.f * fabsf(hv));
        }
    }
    __syncthreads();

    // ---- phase 2: one wave per token ----
    const int tok = blockIdx.x * 4 + wave;

    float s[CD];
    int jstar = 0;
    #pragma unroll
    for (int c = 0; c < CD; ++c) {
        const bool pos = h_lds[wave][c] > 0.f;
        s[c] = pos ? 1.f : -1.f;
        jstar |= (pos ? 1 : 0) << (13 - c);
    }
    if (lane == 0) idx_out[tok] = (float)jstar;

    // out = s @ W_out^T + b_out; W_out rows are L1-resident (28 KB total)
    #pragma unroll
    for (int r = 0; r < 8; ++r) {
        const int d = r * 64 + lane;
        const float2* wp2 = (const float2*)(W_out + (size_t)d * CD);
        float v = b_out[d];
        #pragma unroll
        for (int q = 0; q < 7; ++q) {
            const float2 w = wp2[q];
            v = fmaf(s[2 * q],     w.x, v);
            v = fmaf(s[2 * q + 1], w.y, v);
        }
        out[(size_t)tok * DIM + d] = v;
    }

    // sparse clipped-softmax: p = (prod over flipped hot bits of f)/Z
    // identity: sum_j p*log(clip(p,eps)) = LOG_EPS + sum_enum p*(max(log p,LOG_EPS)-LOG_EPS)
    float Z = 1.f, commit = 0.f;
    int hot = 0;
    #pragma unroll
    for (int c = 0; c < CD; ++c) {
        const float fv = f_lds[wave][c];
        const float ah = fabsf(h_lds[wave][c]);
        const float dd = ah - 1.f;           // (h - sign(h))^2 == (|h|-1)^2
        commit = fmaf(dd, dd, commit);
        Z *= 1.f + fv;
        hot |= (fv >= PTHRESH ? 1 : 0) << c;
    }
    const float invZ = 1.f / Z;
    const int nmask = 1 << __popc(hot);

    float ent = 0.f;
    for (int base = 0; base < nmask; base += 64) {
        const int si = base + lane;           // subset index over hot bits
        float prod = 1.f;
        int flip = 0, pos = 0;
        #pragma unroll
        for (int c = 0; c < CD; ++c) {
            if ((hot >> c) & 1) {
                if ((si >> pos) & 1) {
                    prod *= f_lds[wave][c];
                    flip |= 1 << (13 - c);
                }
                ++pos;
            }
        }
        if (si < nmask) {
            const float p = prod * invZ;
            if (p >= PTHRESH) {
                ent = fmaf(p, fmaxf(__logf(p), LOG_EPS) - LOG_EPS, ent);
                atomicAdd(&ws[jstar ^ flip], p);
            }
        }
    }
    #pragma unroll
    for (int off = 32; off; off >>= 1) ent += __shfl_xor(ent, off);
    if (lane == 0) { entred[wave] = ent; comred[wave] = commit; }
    __syncthreads();
    if (tid == 0) {
        ws[WS_ENT + blockIdx.x] = (entred[0] + entred[1]) + (entred[2] + entred[3]);
        ws[WS_COM + blockIdx.x] = (comred[0] + comred[1]) + (comred[2] + comred[3]);
    }
}

__global__ __launch_bounds__(1024) void k_final(
    const float* __restrict__ ws, float* __restrict__ aux_out)
{
    __shared__ float r1[1024], r2[1024], r3[1024];
    const int tid = threadIdx.x;
    float acc = 0.f;
    #pragma unroll
    for (int k = 0; k < 16; ++k) {
        const float ap = ws[tid + k * 1024] * (1.f / 8192.f);
        acc = fmaf(ap, __logf(fmaxf(ap, EPS)), acc);
    }
    float entp = ws[WS_ENT + tid] + ws[WS_ENT + tid + 1024];
    float comp = ws[WS_COM + tid] + ws[WS_COM + tid + 1024];
    r1[tid] = acc; r2[tid] = entp; r3[tid] = comp;
    __syncthreads();
    for (int s = 512; s > 0; s >>= 1) {
        if (tid < s) {
            r1[tid] += r1[tid + s];
            r2[tid] += r2[tid + s];
            r3[tid] += r3[tid + s];
        }
        __syncthreads();
    }
    if (tid == 0) {
        const float cbH = -r1[0];
        // mean_t sum_j p log(clip p) == r2/NTOK + LOG_EPS
        const float psH = -(r2[0] * (1.f / 8192.f) + LOG_EPS);
        const float commit = r3[0] * (1.f / (8192.f * 14.f));
        aux_out[0] = (psH - cbH) * 0.1f + commit * 0.25f;
    }
}

extern "C" void kernel_launch(void* const* d_in, const int* in_sizes, int n_in,
                              void* d_out, int out_size, void* d_ws, size_t ws_size,
                              hipStream_t stream) {
    const float* x     = (const float*)d_in[0];
    const float* W_in  = (const float*)d_in[1];
    const float* b_in  = (const float*)d_in[2];
    const float* W_out = (const float*)d_in[3];
    const float* b_out = (const float*)d_in[4];
    // d_in[5] (codebook) is implicit in the factorized math.

    float* out     = (float*)d_out;                 // [4*2048*512]
    float* idx_out = out + (size_t)NTOK * DIM;      // [8192] as float
    float* aux_out = idx_out + NTOK;                // [1]
    float* ws      = (float*)d_ws;

    hipMemsetAsync(ws, 0, NCODES * sizeof(float), stream);  // zero avg_prob bins
    hipLaunchKernelGGL(k_main, dim3(NBLK), dim3(256), 0, stream,
                       x, W_in, b_in, W_out, b_out, out, idx_out, ws);
    hipLaunchKernelGGL(k_final, dim3(1), dim3(1024), 0, stream, ws, aux_out);
}